// Round 4
// baseline (1591.276 us; speedup 1.0000x reference)
//
#include <hip/hip_runtime.h>
#include <hip/hip_fp16.h>

#define B_ 256
#define S_ 512
#define D_ 200
#define H_ 256

typedef _Float16 half4_t __attribute__((ext_vector_type(4)));
typedef _Float16 half8_t __attribute__((ext_vector_type(8)));
typedef float    floatx4 __attribute__((ext_vector_type(4)));
typedef unsigned long long u64;

#define AGENT __HIP_MEMORY_SCOPE_AGENT

__device__ __forceinline__ float fast_sig(float x) {
    return 1.f / (1.f + __expf(-x));
}
__device__ __forceinline__ float fast_tanh(float x) {
    x = fminf(15.f, fmaxf(-15.f, x));
    float e = __expf(2.f * x);
    return (e - 1.f) / (e + 1.f);
}

// ---------------------------------------------------------------------------
// prep: build fp16 weight layouts in workspace.  (unchanged)
// ---------------------------------------------------------------------------
__global__ void prep(const float* __restrict__ Wi, const float* __restrict__ Wf,
                     const float* __restrict__ Wo, const float* __restrict__ Wz,
                     _Float16* __restrict__ W4T, _Float16* __restrict__ WhT) {
    const int n = blockIdx.x;      // 0..1023
    const int t = threadIdx.x;     // 0..255
    const int g = n >> 8, j = n & 255;
    const float* Wg = (g == 0) ? Wi : (g == 1) ? Wf : (g == 2) ? Wo : Wz;
    if (t < 224)
        W4T[(size_t)n * 224 + t] = (t < D_) ? (_Float16)Wg[t * 256 + j] : (_Float16)0.f;
    WhT[(size_t)n * 256 + t] = (_Float16)Wg[(D_ + t) * 256 + j];
}

// ---------------------------------------------------------------------------
// gemm_x: unchanged (verified, ~230us).
// ---------------------------------------------------------------------------
__global__ __launch_bounds__(256) void gemm_x(const float* __restrict__ X,
                                              const _Float16* __restrict__ W4T,
                                              const float* __restrict__ bi,
                                              const float* __restrict__ bfg,
                                              const float* __restrict__ bo,
                                              const float* __restrict__ bz,
                                              _Float16* __restrict__ G) {
    __shared__ __align__(16) _Float16 As[128][40];
    __shared__ __align__(16) _Float16 Bs[128][40];

    const int mt = blockIdx.x >> 3;
    const int nt = blockIdx.x & 7;
    const int m0 = mt * 128, n0 = nt * 128;
    const int tid  = threadIdx.x;
    const int lane = tid & 63, wave = tid >> 6;
    const int quad = lane >> 4, l16 = lane & 15;
    const int mq = (wave & 1) * 64, nq = (wave >> 1) * 64;

    floatx4 acc[4][4];
#pragma unroll
    for (int i = 0; i < 4; ++i)
#pragma unroll
        for (int j = 0; j < 4; ++j) acc[i][j] = (floatx4){0.f, 0.f, 0.f, 0.f};

    const int srow = tid >> 1;
    const int koff = (tid & 1) * 16;

    for (int kt = 0; kt < 7; ++kt) {
        const int k0 = kt * 32;
        {
            const int m = m0 + srow;
            const float* xr = X + (size_t)m * D_ + (k0 + koff);
            half8_t v0, v1;
            if (m < B_ * S_ - 1) {
                const floatx4* xp = (const floatx4*)xr;
                floatx4 f0 = xp[0], f1 = xp[1], f2 = xp[2], f3 = xp[3];
#pragma unroll
                for (int i = 0; i < 4; ++i) {
                    v0[i]     = (_Float16)f0[i];
                    v0[4 + i] = (_Float16)f1[i];
                    v1[i]     = (_Float16)f2[i];
                    v1[4 + i] = (_Float16)f3[i];
                }
            } else {
#pragma unroll
                for (int i = 0; i < 8; ++i) {
                    int k = k0 + koff + i;
                    v0[i] = (k < D_) ? (_Float16)xr[i] : (_Float16)0.f;
                }
#pragma unroll
                for (int i = 0; i < 8; ++i) {
                    int k = k0 + koff + 8 + i;
                    v1[i] = (k < D_) ? (_Float16)xr[8 + i] : (_Float16)0.f;
                }
            }
            *(half8_t*)&As[srow][koff]     = v0;
            *(half8_t*)&As[srow][koff + 8] = v1;
        }
        {
            const _Float16* wr = W4T + (size_t)(n0 + srow) * 224 + (k0 + koff);
            const half8_t* wp = (const half8_t*)wr;
            *(half8_t*)&Bs[srow][koff]     = wp[0];
            *(half8_t*)&Bs[srow][koff + 8] = wp[1];
        }
        __syncthreads();

        half8_t af[4], bf[4];
#pragma unroll
        for (int i = 0; i < 4; ++i) af[i] = *(const half8_t*)&As[mq + i * 16 + l16][quad * 8];
#pragma unroll
        for (int i = 0; i < 4; ++i) bf[i] = *(const half8_t*)&Bs[nq + i * 16 + l16][quad * 8];
#pragma unroll
        for (int mi = 0; mi < 4; ++mi)
#pragma unroll
            for (int ni = 0; ni < 4; ++ni)
                acc[mi][ni] = __builtin_amdgcn_mfma_f32_16x16x32_f16(af[mi], bf[ni], acc[mi][ni], 0, 0, 0);
        __syncthreads();
    }

#pragma unroll
    for (int ni = 0; ni < 4; ++ni) {
        const int gcol = n0 + nq + ni * 16 + l16;
        const int g = gcol >> 8, j = gcol & 255;
        const float bv = ((g == 0) ? bi : (g == 1) ? bfg : (g == 2) ? bo : bz)[j];
#pragma unroll
        for (int mi = 0; mi < 4; ++mi)
#pragma unroll
            for (int r = 0; r < 4; ++r) {
                const int grow = m0 + mq + mi * 16 + quad * 4 + r;
                G[(size_t)grow * 1024 + gcol] = (_Float16)(acc[mi][ni][r] + bv);
            }
    }
}

// ---------------------------------------------------------------------------
// zero_exch: clear all exchange words with agent-scope atomic stores.
// ---------------------------------------------------------------------------
__global__ void zero_exch(u64* __restrict__ ebuf) {
    const int i = blockIdx.x * 512 + threadIdx.x;
    __hip_atomic_store(ebuf + i, 0ull, __ATOMIC_RELAXED, AGENT);
}

// ---------------------------------------------------------------------------
// lstm_rec5: rec4 + counted-vmcnt discipline (T3/T4 pattern).
//   rec4's 4300cy/step overhead decomposed into 3 vmcnt(0) drains:
//     (a) remote loads issued AFTER the G prefetch -> the wait for remote
//         also drained ~900cy of HBM latency        [fix: remote FIRST]
//     (b) __syncthreads() == s_waitcnt vmcnt(0); barrier M drained the
//         publish store's LLC ack mid-step           [fix: raw s_barrier]
//     (c) barrier E drained the G prefetch           [fix: raw s_barrier]
//   Now: raw __builtin_amdgcn_s_barrier() + explicit lgkmcnt(0) only; the
//   publish store and G prefetch stay in flight across BOTH barriers for a
//   full step; the only VMEM wait on the critical path is the remote-word
//   wait, covered by the local-half MFMA phase.
//   Everything else verbatim from the (passing) rec4 core.
// ---------------------------------------------------------------------------
__global__ __launch_bounds__(512, 2) void lstm_rec5(
    const _Float16* __restrict__ G,     // [B][S][1024] plain, bias folded
    const _Float16* __restrict__ WhT,   // [1024][256] fp16
    const float* __restrict__ mask,     // [B][S] fp32
    u64* __restrict__ ebuf,             // [128][2 q][2 par][2 bat][64] u64
    float* __restrict__ out)            // [B][256] fp32
{
    __shared__ __align__(16) unsigned hL[2][2][80];  // local h  [par][bat][pad80]
    __shared__ __align__(16) unsigned hR[2][2][80];  // remote h [par][bat][pad80]
    __shared__ float mS[2][S_];                      // 4 KB

    const int bid  = blockIdx.x;
    const int q    = (bid >> 3) & 1;                    // half index within pair
    const int g    = (bid & 7) | ((bid >> 4) << 3);     // pair id 0..127
    const int b0   = 2 * g;
    const int t    = threadIdx.x;
    const int w    = t >> 6;
    const int lane = t & 63;
    const int l16  = lane & 15, quad = lane >> 4;
    const int bat  = l16 & 1;
    const int rp   = (l16 >> 1) & 1;

    const int s_lo = 16 * q + quad;
    const int s_hi = 16 - 16 * q + quad;

#define DECLA(gi) half8_t A##gi##_0, A##gi##_1, A##gi##_2, A##gi##_3, \
                          A##gi##_4, A##gi##_5, A##gi##_6, A##gi##_7
#define LOADA(gi) do {                                                          \
        const half8_t* p = (const half8_t*)(WhT +                               \
            (size_t)((gi) * 256 + 128 * q + 16 * w + l16) * 256);               \
        A##gi##_0 = p[s_lo];      A##gi##_1 = p[s_lo + 4];                      \
        A##gi##_2 = p[s_lo + 8];  A##gi##_3 = p[s_lo + 12];                     \
        A##gi##_4 = p[s_hi];      A##gi##_5 = p[s_hi + 4];                      \
        A##gi##_6 = p[s_hi + 8];  A##gi##_7 = p[s_hi + 12];                     \
        asm volatile("" : "+v"(A##gi##_0), "+v"(A##gi##_1), "+v"(A##gi##_2),    \
                          "+v"(A##gi##_3), "+v"(A##gi##_4), "+v"(A##gi##_5),    \
                          "+v"(A##gi##_6), "+v"(A##gi##_7));                    \
    } while (0)

    DECLA(0); DECLA(1); DECLA(2); DECLA(3);
    LOADA(0); LOADA(1); LOADA(2); LOADA(3);

    mS[0][t] = mask[(size_t)b0 * S_ + t];
    mS[1][t] = mask[(size_t)(b0 + 1) * S_ + t];

    u64* eb_own = ebuf + (size_t)(g * 2 + q) * 256;       // [2 par][2 bat][64]
    u64* eb_rem = ebuf + (size_t)(g * 2 + (1 - q)) * 256;

    const _Float16* Gb = G + ((size_t)(b0 + bat) << 19) + (128 * q + 16 * w + 4 * quad);
    half4_t N0, N1, N2, N3;
#define GLOAD(sidx) do { const _Float16* gp = Gb + ((size_t)(sidx) << 10);      \
        N0 = *(const half4_t*)(gp);       N1 = *(const half4_t*)(gp + 256);     \
        N2 = *(const half4_t*)(gp + 512); N3 = *(const half4_t*)(gp + 768);     \
    } while (0)

#define MFS(f, Bv)                                                              \
    C0 = __builtin_amdgcn_mfma_f32_16x16x32_f16(A0_##f, Bv, C0, 0, 0, 0);       \
    C1 = __builtin_amdgcn_mfma_f32_16x16x32_f16(A1_##f, Bv, C1, 0, 0, 0);       \
    C2 = __builtin_amdgcn_mfma_f32_16x16x32_f16(A2_##f, Bv, C2, 0, 0, 0);       \
    C3 = __builtin_amdgcn_mfma_f32_16x16x32_f16(A3_##f, Bv, C3, 0, 0, 0)

    GLOAD(0);
    float cst0 = 0.f, cst1 = 0.f, acc0 = 0.f, acc1 = 0.f, msum = 0.f;
    const int jj = 8 * w + 2 * quad + rp;   // publish word index (0..63)
    u64 pub = 0;                            // {h pair, step} held across barrier
    __syncthreads();                        // full sync once (mS, hL init ordering)

    for (int s = 0; s < S_; ++s) {
        const int par = s & 1;

        // 1) publish h_s (computed last iter); relaxed store, never drained
        //    by a barrier in this loop -> ack has a full step of slack.
        if (s > 0 && l16 < 4)
            __hip_atomic_store(eb_own + (par << 7) + (bat << 6) + jj, pub,
                               __ATOMIC_RELAXED, AGENT);

        // 2) remote h loads issued FIRST (before G prefetch) so the wait for
        //    them does not drain the HBM loads (vmcnt is in-order).
        const u64* rb = eb_rem + ((size_t)par << 7) + 2 * lane;
        u64 w0v = 0, w1v = 0;
        if (s > 0 && w == 0) {
            w0v = __hip_atomic_load(rb,     __ATOMIC_RELAXED, AGENT);
            w1v = __hip_atomic_load(rb + 1, __ATOMIC_RELAXED, AGENT);
        }
        __builtin_amdgcn_sched_barrier(0);

        // 3) C init from prefetched G (prev step's GLOAD, long since landed)
        floatx4 C0, C1, C2, C3;
#pragma unroll
        for (int k = 0; k < 4; ++k) {
            C0[k] = (float)N0[k]; C1[k] = (float)N1[k];
            C2[k] = (float)N2[k]; C3[k] = (float)N3[k];
        }
        // 4) G prefetch for next step (younger than remote loads in vmcnt)
        GLOAD((s < S_ - 1) ? s + 1 : s);

        if (s > 0) {
            // 5) local-half B fragments + MFMAs (covers the LLC round trip)
            const unsigned* hl = &hL[par][bat][0];
            half8_t BL0 = *(const half8_t*)(hl + 4 * quad);
            half8_t BL1 = *(const half8_t*)(hl + 16 + 4 * quad);
            half8_t BL2 = *(const half8_t*)(hl + 32 + 4 * quad);
            half8_t BL3 = *(const half8_t*)(hl + 48 + 4 * quad);
            MFS(0, BL0); MFS(1, BL1); MFS(2, BL2); MFS(3, BL3);

            // 6) consume remote words (compiler waits vmcnt(4): G still flying),
            //    validate step tags, park remote half into LDS.
            if (w == 0) {
                const unsigned tgt = (unsigned)s;
                while (__any(((unsigned)(w0v >> 32) != tgt) |
                             ((unsigned)(w1v >> 32) != tgt))) {
                    w0v = __hip_atomic_load(rb,     __ATOMIC_RELAXED, AGENT);
                    w1v = __hip_atomic_load(rb + 1, __ATOMIC_RELAXED, AGENT);
                }
                unsigned* hw = &hR[par][lane >> 5][2 * (lane & 31)];
                hw[0] = (unsigned)w0v;
                hw[1] = (unsigned)w1v;
            }
            // LDS-only drain + raw barrier (no vmcnt(0): G/publish stay in flight)
            asm volatile("s_waitcnt lgkmcnt(0)" ::: "memory");
            __builtin_amdgcn_sched_barrier(0);
            __builtin_amdgcn_s_barrier();      // barrier M: hR visible
            __builtin_amdgcn_sched_barrier(0);

            const unsigned* hr = &hR[par][bat][0];
            half8_t BR0 = *(const half8_t*)(hr + 4 * quad);
            half8_t BR1 = *(const half8_t*)(hr + 16 + 4 * quad);
            half8_t BR2 = *(const half8_t*)(hr + 32 + 4 * quad);
            half8_t BR3 = *(const half8_t*)(hr + 48 + 4 * quad);
            MFS(4, BR0); MFS(5, BR1); MFS(6, BR2); MFS(7, BR3);
        }

        // 7) gates: lane owns (batch=bat, j = 128q + 16w + 4quad + 2rp, +1)
        const float m0 = mS[bat][s];
        float pi0 = rp ? C0[2] : C0[0], pi1 = rp ? C0[3] : C0[1];
        float pf0 = rp ? C1[2] : C1[0], pf1 = rp ? C1[3] : C1[1];
        float po0 = rp ? C2[2] : C2[0], po1 = rp ? C2[3] : C2[1];
        float pz0 = rp ? C3[2] : C3[0], pz1 = rp ? C3[3] : C3[1];
        const float i0 = fast_sig(pi0), f0 = fast_sig(pf0);
        const float o0 = fast_sig(po0), z0 = fast_tanh(pz0);
        const float i1 = fast_sig(pi1), f1 = fast_sig(pf1);
        const float o1 = fast_sig(po1), z1 = fast_tanh(pz1);
        cst0 = i0 * z0 + f0 * cst0;
        cst1 = i1 * z1 + f1 * cst1;
        const float h0 = o0 * fast_tanh(cst0);
        const float h1 = o1 * fast_tanh(cst1);
        acc0 += m0 * h0; acc1 += m0 * h1; msum += m0;

        // 8) stage h_{s+1} to LDS; global publish deferred to next step top
        const int par1 = (s + 1) & 1;
        union { _Float16 hh[2]; unsigned u32; } pk;
        pk.hh[0] = (_Float16)h0; pk.hh[1] = (_Float16)h1;
        if (l16 < 4)
            hL[par1][bat][jj] = pk.u32;
        pub = (u64)pk.u32 | ((u64)(unsigned)(s + 1) << 32);

        asm volatile("s_waitcnt lgkmcnt(0)" ::: "memory");
        __builtin_amdgcn_sched_barrier(0);
        __builtin_amdgcn_s_barrier();          // barrier E: hL visible
        __builtin_amdgcn_sched_barrier(0);
    }
#undef DECLA
#undef LOADA
#undef GLOAD
#undef MFS

    if (l16 < 4) {
        const int jg = 128 * q + 16 * w + 4 * quad + 2 * rp;
        const float inv = 1.f / msum;
        out[(b0 + bat) * 256 + jg]     = acc0 * inv;
        out[(b0 + bat) * 256 + jg + 1] = acc1 * inv;
    }
}

extern "C" void kernel_launch(void* const* d_in, const int* in_sizes, int n_in,
                              void* d_out, int out_size, void* d_ws, size_t ws_size,
                              hipStream_t stream) {
    const float* X    = (const float*)d_in[0];
    const float* mask = (const float*)d_in[1];
    const float* Wi   = (const float*)d_in[2];
    const float* bi   = (const float*)d_in[3];
    const float* Wf   = (const float*)d_in[4];
    const float* bf   = (const float*)d_in[5];
    const float* Wo   = (const float*)d_in[6];
    const float* bo   = (const float*)d_in[7];
    const float* Wz   = (const float*)d_in[8];
    const float* bz   = (const float*)d_in[9];
    float* out = (float*)d_out;

    char* ws = (char*)d_ws;
    _Float16* G   = (_Float16*)ws;                                   // 268,435,456 B
    _Float16* W4T = (_Float16*)(ws + (size_t)B_ * S_ * 1024 * 2);    //     458,752 B
    _Float16* WhT = (_Float16*)(ws + (size_t)B_ * S_ * 1024 * 2 + (size_t)1024 * 224 * 2);
    // exchange buffer lives after WhT: 65536 u64 = 512 KB
    u64* ebuf = (u64*)(ws + (size_t)B_ * S_ * 1024 * 2
                          + (size_t)1024 * 224 * 2
                          + (size_t)1024 * 256 * 2);

    hipLaunchKernelGGL(prep,      dim3(1024), dim3(256), 0, stream, Wi, Wf, Wo, Wz, W4T, WhT);
    hipLaunchKernelGGL(gemm_x,    dim3(8192), dim3(256), 0, stream, X, W4T, bi, bf, bo, bz, G);
    hipLaunchKernelGGL(zero_exch, dim3(128),  dim3(512), 0, stream, ebuf);
    hipLaunchKernelGGL(lstm_rec5, dim3(256),  dim3(512), 0, stream, G, WhT, mask, ebuf, out);
}